// Round 6
// baseline (373.051 us; speedup 1.0000x reference)
//
#include <hip/hip_runtime.h>

// FWHT over last dim 4096 of fp32, rows = total/4096.
// Radix-16^3: one 256-thread block per row, 16 floats/thread, three 4-bit
// register FWHT phases (bits 0-3, 4-7, 8-11) with LDS transposes between.
// Butterfly order/pairing identical to the float32 reference (h ascending)
// -> bit-exact output (absmax = 0).
//
// v6: vectorized STORES. v1/v2/v3/v5 (1-wave, 32-wave/CU, prefetch, true
// glds pipeline) ALL land at ~80 us / 2.5 TB/s -> latency/occupancy/barrier
// theories are dead. The invariant: every store was a scalar dword
// (4 B/lane), and measured precedent (m18 scalar 2.35 TB/s vs m146/m13
// vectorized 4.9-6.3 TB/s) says 4B/lane memory ops park at ~2.4 TB/s.
// Fix: add a third transpose T3 so each thread ends with 16 CONTIGUOUS
// floats and stores 4x nontemporal dwordx4 (wave = 4 KB contiguous).
// Everything else is the simplest proven structure (plain __syncthreads,
// no persistence, no glds) so store width is the only active variable.
// (v6b: use clang ext_vector f32x4 for the nontemporal store —
//  __builtin_nontemporal_store rejects HIP_vector_type float4.)
//
// LDS: ONE 5120-float buffer (20,480 B; 8 blocks x 20,480 = 160 KiB exact).
//   T1 (pitch 17): element n at 17*(n>>4) + (n&15)
//       write 17t+j (contiguous-16), read 272*t_hi + 17*j + t_lo
//   T2 (pitch 17): element n at 17*(n&255) + (n>>8)
//       write 272*j + 17*t_lo + t_hi, read 17t + j
//   T3 (pitch 20): element n at 20*(n>>4) + (n&15)
//       write 320*j + 20*t_hi + t_lo (n = 256j + t)
//       read  20t + j  -> byte 80t+4j: 16B-aligned -> 4x b128; 16-lane
//       group chunk index 5t+q covers all 8 bank-groups 2x (5 coprime 8)
//       -> conflict-free.

typedef float f32x4 __attribute__((ext_vector_type(4)));

constexpr int DIM = 4096;
constexpr int P1 = 17;   // T1/T2 pitch (floats per 16-float row)
constexpr int P3 = 20;   // T3 pitch: 80 B rows -> 16B-aligned b128 reads

__device__ __forceinline__ void fwht16(float v[16]) {
#pragma unroll
    for (int h = 1; h < 16; h <<= 1) {
#pragma unroll
        for (int i = 0; i < 16; i += 2 * h) {
#pragma unroll
            for (int k = 0; k < h; ++k) {
                float a = v[i + k];
                float b = v[i + k + h];
                v[i + k]     = a + b;
                v[i + k + h] = a - b;
            }
        }
    }
}

__global__ __launch_bounds__(256, 8) void fwht4096_kernel(const float* __restrict__ x,
                                                          float* __restrict__ y) {
    __shared__ __align__(16) float tbuf[5120];  // 20,480 B shared by T1/T2/T3
    const int t = threadIdx.x;                  // 0..255
    const long long row = blockIdx.x;           // one row per block
    const int t_hi = t >> 4;
    const int t_lo = t & 15;

    float v[16];

    // ---- load: thread owns n = 16t + j (4 x dwordx4, wave = 4 KB) ----
    {
        const float4* src = reinterpret_cast<const float4*>(x + row * DIM + t * 16);
#pragma unroll
        for (int q = 0; q < 4; ++q) {
            float4 f = src[q];
            v[4 * q + 0] = f.x;
            v[4 * q + 1] = f.y;
            v[4 * q + 2] = f.z;
            v[4 * q + 3] = f.w;
        }
    }

    // ---- phase A: bits 0..3 (n = 16t + j) ----
    fwht16(v);

    // ---- transpose 1: write n = 16t + j at 17t + j ----
    {
        float* wp = tbuf + P1 * t;
#pragma unroll
        for (int j = 0; j < 16; ++j) wp[j] = v[j];
    }
    __syncthreads();
    // read n' = (t_hi<<8)|(j<<4)|t_lo -> 272*t_hi + 17*j + t_lo
    {
        const float* rp = tbuf + (P1 * 16) * t_hi + t_lo;
#pragma unroll
        for (int j = 0; j < 16; ++j) v[j] = rp[P1 * j];
    }

    // ---- phase B: bits 4..7 ----
    fwht16(v);

    __syncthreads();  // all T1 reads done before relayout

    // ---- transpose 2: value j (n' = (t_hi<<8)|(j<<4)|t_lo) at
    //      272*j + 17*t_lo + t_hi ----
    {
        float* wp = tbuf + P1 * t_lo + t_hi;
#pragma unroll
        for (int j = 0; j < 16; ++j) wp[(P1 * 16) * j] = v[j];
    }
    __syncthreads();
    // read n'' = (j<<8) | t -> 17t + j (contiguous)
    {
        const float* rp = tbuf + P1 * t;
#pragma unroll
        for (int j = 0; j < 16; ++j) v[j] = rp[j];
    }

    // ---- phase C: bits 8..11 (value j is element n = 256j + t) ----
    fwht16(v);

    __syncthreads();  // all T2 reads done before T3 overwrites tbuf

    // ---- transpose 3: element n = 256j + t at 20*(n>>4) + (n&15)
    //      = 320*j + 20*t_hi + t_lo ----
    {
        float* wp = tbuf + P3 * t_hi + t_lo;
#pragma unroll
        for (int j = 0; j < 16; ++j) wp[(P3 * 16) * j] = v[j];
    }
    __syncthreads();

    // ---- scale + vectorized nontemporal store: thread owns n = 16t..16t+15,
    //      read at 20t + j (4 x b128, conflict-free), store 4 x dwordx4 ----
    const float scale = 0x1p-39f;  // 2^-(L(L+1)/4), L = 12
    {
        const float4* rp = reinterpret_cast<const float4*>(tbuf + P3 * t);
        f32x4* dst = reinterpret_cast<f32x4*>(y + row * DIM + t * 16);
#pragma unroll
        for (int q = 0; q < 4; ++q) {
            float4 f = rp[q];
            f32x4 o;
            o.x = f.x * scale;
            o.y = f.y * scale;
            o.z = f.z * scale;
            o.w = f.w * scale;
            __builtin_nontemporal_store(o, dst + q);
        }
    }
}

extern "C" void kernel_launch(void* const* d_in, const int* in_sizes, int n_in,
                              void* d_out, int out_size, void* d_ws, size_t ws_size,
                              hipStream_t stream) {
    const float* x = (const float*)d_in[0];
    float* y = (float*)d_out;
    const int nrows = in_sizes[0] / DIM;  // 8192
    fwht4096_kernel<<<nrows, 256, 0, stream>>>(x, y);
}

// Round 7
// 229.111 us; speedup vs baseline: 1.6283x; 1.6283x over previous
//
#include <hip/hip_runtime.h>

// FWHT over last dim 4096 of fp32, rows = total/4096.
// Radix-16^3: one 256-thread block per row, 16 floats/thread, three 4-bit
// register FWHT phases (bits 0-3, 4-7, 8-11) with LDS transposes between.
// Butterfly order/pairing identical to the float32 reference (h ascending)
// -> bit-exact output (absmax = 0).
//
// v7: WAVE-coalesced vectorized stores. v6's T3 made stores per-THREAD
// contiguous -> each wave store instr touched 64 lines x 16B, and NT
// (no L2 merge) inflated WRITE_SIZE 131->357 MB, dur 80->225 us. v7's T3
// is a LINEAR LDS image: scalar writes tbuf[n]=v (bank = t mod 32, 2-way,
// free), then each wave reads 4 x ds_read_b128 contiguous and stores
// 4 x NT dwordx4 with each wave instr writing 1 KB fully contiguous.
// Store instr footprint: 1 KB/wave (vs 256 B scalar in v1-v5, which all
// parked at ~2.4 TB/s -- the scalar-store band; m18 vs m146 precedent).
//
// LDS: one 5120-float buffer (20,480 B; 8 blocks/CU = 160 KiB exact).
//   T1 (pitch 17): element n at 17*(n>>4) + (n&15)
//       write 17t+j (contiguous-16), read 272*t_hi + 17*j + t_lo (2-way)
//   T2 (pitch 17): element n at 17*(n&255) + (n>>8)
//       write 272*j + 17*t_lo + t_hi (2-way), read 17t + j
//   T3 (linear):   element n at tbuf[n]
//       write 256j + t (scalar, 2-way), read b128 at 1024w+256q+4l
//       (consecutive lanes contiguous 16B -> conflict-free)

typedef float f32x4 __attribute__((ext_vector_type(4)));

constexpr int DIM = 4096;
constexpr int P1 = 17;   // T1/T2 pitch (floats per 16-float row)

__device__ __forceinline__ void fwht16(float v[16]) {
#pragma unroll
    for (int h = 1; h < 16; h <<= 1) {
#pragma unroll
        for (int i = 0; i < 16; i += 2 * h) {
#pragma unroll
            for (int k = 0; k < h; ++k) {
                float a = v[i + k];
                float b = v[i + k + h];
                v[i + k]     = a + b;
                v[i + k + h] = a - b;
            }
        }
    }
}

__global__ __launch_bounds__(256, 4) void fwht4096_kernel(const float* __restrict__ x,
                                                          float* __restrict__ y) {
    __shared__ __align__(16) float tbuf[5120];  // 20,480 B shared by T1/T2/T3
    const int t = threadIdx.x;                  // 0..255
    const long long row = blockIdx.x;           // one row per block
    const int t_hi = t >> 4;
    const int t_lo = t & 15;
    const int w = t >> 6;                       // wave id 0..3
    const int l = t & 63;                       // lane id 0..63

    float v[16];

    // ---- load: thread owns n = 16t + j (4 x dwordx4, wave = 4 KB) ----
    {
        const float4* src = reinterpret_cast<const float4*>(x + row * DIM + t * 16);
#pragma unroll
        for (int q = 0; q < 4; ++q) {
            float4 f = src[q];
            v[4 * q + 0] = f.x;
            v[4 * q + 1] = f.y;
            v[4 * q + 2] = f.z;
            v[4 * q + 3] = f.w;
        }
    }

    // ---- phase A: bits 0..3 (n = 16t + j) ----
    fwht16(v);

    // ---- transpose 1: write n = 16t + j at 17t + j ----
    {
        float* wp = tbuf + P1 * t;
#pragma unroll
        for (int j = 0; j < 16; ++j) wp[j] = v[j];
    }
    __syncthreads();
    // read n' = (t_hi<<8)|(j<<4)|t_lo -> 272*t_hi + 17*j + t_lo
    {
        const float* rp = tbuf + (P1 * 16) * t_hi + t_lo;
#pragma unroll
        for (int j = 0; j < 16; ++j) v[j] = rp[P1 * j];
    }

    // ---- phase B: bits 4..7 ----
    fwht16(v);

    __syncthreads();  // all T1 reads done before relayout

    // ---- transpose 2: value j (n' = (t_hi<<8)|(j<<4)|t_lo) at
    //      272*j + 17*t_lo + t_hi ----
    {
        float* wp = tbuf + P1 * t_lo + t_hi;
#pragma unroll
        for (int j = 0; j < 16; ++j) wp[(P1 * 16) * j] = v[j];
    }
    __syncthreads();
    // read n'' = (j<<8) | t -> 17t + j (contiguous)
    {
        const float* rp = tbuf + P1 * t;
#pragma unroll
        for (int j = 0; j < 16; ++j) v[j] = rp[j];
    }

    // ---- phase C: bits 8..11 (value j is element n = 256j + t) ----
    fwht16(v);

    __syncthreads();  // all T2 reads done before T3 overwrites tbuf

    // ---- transpose 3 (linear): element n = 256j + t at tbuf[n] ----
    {
#pragma unroll
        for (int j = 0; j < 16; ++j) tbuf[256 * j + t] = v[j];
    }
    __syncthreads();

    // ---- scale + wave-coalesced NT store: instr q reads b128 at
    //      1024w + 256q + 4l (contiguous) and writes 1 KB/wave ----
    const float scale = 0x1p-39f;  // 2^-(L(L+1)/4), L = 12
    {
        const float4* rp = reinterpret_cast<const float4*>(tbuf + 1024 * w + 4 * l);
        f32x4* dst = reinterpret_cast<f32x4*>(y + row * DIM + 1024 * w + 4 * l);
#pragma unroll
        for (int q = 0; q < 4; ++q) {
            float4 f = rp[64 * q];  // 64 float4s = 256 floats per q step
            f32x4 o;
            o.x = f.x * scale;
            o.y = f.y * scale;
            o.z = f.z * scale;
            o.w = f.w * scale;
            __builtin_nontemporal_store(o, dst + 64 * q);
        }
    }
}

extern "C" void kernel_launch(void* const* d_in, const int* in_sizes, int n_in,
                              void* d_out, int out_size, void* d_ws, size_t ws_size,
                              hipStream_t stream) {
    const float* x = (const float*)d_in[0];
    float* y = (float*)d_out;
    const int nrows = in_sizes[0] / DIM;  // 8192
    fwht4096_kernel<<<nrows, 256, 0, stream>>>(x, y);
}

// Round 8
// 228.650 us; speedup vs baseline: 1.6315x; 1.0020x over previous
//
#include <hip/hip_runtime.h>

// FWHT over last dim 4096 of fp32, rows = total/4096.
// Radix-16^3 per row: 256-thread block, 16 floats/thread, three 4-bit
// register FWHT phases with pitch-17 LDS transposes. Butterfly order
// identical to the float32 reference -> bit-exact (absmax = 0).
//
// v8: TWO rows per block, statically phase-interleaved. Ledger: occupancy
// (v2), true glds pipelining (v5), store width (v7) all neutral at ~80 us
// while HBM(~32us) + DS(~22us) + VALU(~10us) per-CU budgets SUM to the
// measured time -> pipes run sequentially (phase convoy), not concurrently.
// v8 forces cross-pipe overlap with in-wave ILP: row1's VALU issues in the
// shadow of row0's DS round-trips and vice versa, using two LDS buffers.
// Barriers: 3 per 2 rows (was 2-3 per row), each placed where outstanding
// vmcnt == 0 so __syncthreads' implicit vmcnt(0) drain is free.
// Blocks read rows (2b, 2b+1): 32 KB contiguous per block.
//
// Per-row LDS layout (proven v2 code):
//   T1 (pitch 17): element n at 17*(n>>4) + (n&15)
//       write 17t+j (intra-16-thread-group; no barrier needed)
//       read  272*t_hi + 17*j + t_lo   (2-way bank alias = free)
//   T2 (pitch 17): element n at 17*(n&255) + (n>>8)
//       write 272*j + 17*t_lo + t_hi   (needs block barrier both sides)
//       read  17t + j
// Store: scalar NT dword, n = 256j + t (coalesced 256 B/wave-instr; v7
// proved 1 KB/instr is no faster, so keep the simple form).

constexpr int DIM = 4096;
constexpr int P1 = 17;   // floats per 16-float LDS row (+1 pad)

__device__ __forceinline__ void fwht16(float v[16]) {
#pragma unroll
    for (int h = 1; h < 16; h <<= 1) {
#pragma unroll
        for (int i = 0; i < 16; i += 2 * h) {
#pragma unroll
            for (int k = 0; k < h; ++k) {
                float a = v[i + k];
                float b = v[i + k + h];
                v[i + k]     = a + b;
                v[i + k + h] = a - b;
            }
        }
    }
}

__global__ __launch_bounds__(256, 4) void fwht4096_kernel(const float* __restrict__ x,
                                                          float* __restrict__ y) {
    __shared__ float P[P1 * 256];   // 17,408 B (row 0 of the pair)
    __shared__ float Q[P1 * 256];   // 17,408 B (row 1 of the pair)
    const int t = threadIdx.x;      // 0..255
    const int t_hi = t >> 4;
    const int t_lo = t & 15;
    const long long r0 = 2LL * blockIdx.x;  // rows r0, r0+1

    float u[16], w[16];

    // ---- issue ALL 8 row loads up front (both rows in flight) ----
    float4 La[4], Lb[4];
    {
        const float4* s0 = reinterpret_cast<const float4*>(x + r0 * DIM + t * 16);
        const float4* s1 = reinterpret_cast<const float4*>(x + (r0 + 1) * DIM + t * 16);
#pragma unroll
        for (int q = 0; q < 4; ++q) La[q] = s0[q];
#pragma unroll
        for (int q = 0; q < 4; ++q) Lb[q] = s1[q];
    }

    // ---- A0: unpack + phase A row0 (waits only row0's loads) ----
#pragma unroll
    for (int q = 0; q < 4; ++q) {
        u[4 * q + 0] = La[q].x; u[4 * q + 1] = La[q].y;
        u[4 * q + 2] = La[q].z; u[4 * q + 3] = La[q].w;
    }
    fwht16(u);

    // ---- T1 row0 [P]: write 17t+j, read 272*t_hi + 17j + t_lo ----
    {
        float* wp = P + P1 * t;
#pragma unroll
        for (int j = 0; j < 16; ++j) wp[j] = u[j];
        const float* rp = P + (P1 * 16) * t_hi + t_lo;
#pragma unroll
        for (int j = 0; j < 16; ++j) u[j] = rp[P1 * j];  // in flight
    }

    // ---- A1: unpack + phase A row1 (VALU under row0's DS latency) ----
#pragma unroll
    for (int q = 0; q < 4; ++q) {
        w[4 * q + 0] = Lb[q].x; w[4 * q + 1] = Lb[q].y;
        w[4 * q + 2] = Lb[q].z; w[4 * q + 3] = Lb[q].w;
    }
    fwht16(w);

    // ---- B0 (lgkm wait for T1r0 happens here) ----
    fwht16(u);

    // ---- T1 row1 [Q] ----
    {
        float* wp = Q + P1 * t;
#pragma unroll
        for (int j = 0; j < 16; ++j) wp[j] = w[j];
        const float* rp = Q + (P1 * 16) * t_hi + t_lo;
#pragma unroll
        for (int j = 0; j < 16; ++j) w[j] = rp[P1 * j];  // in flight
    }

    __syncthreads();  // alpha: all T1 reads (P and Q) retired block-wide

    // ---- T2w row0 [P]: value j (n' = (t_hi<<8)|(j<<4)|t_lo) at
    //      272*j + 17*t_lo + t_hi ----
    {
        float* wp = P + P1 * t_lo + t_hi;
#pragma unroll
        for (int j = 0; j < 16; ++j) wp[(P1 * 16) * j] = u[j];
    }

    // ---- B1 (VALU under T2w0 DS; w ready since alpha drained lgkm) ----
    fwht16(w);

    __syncthreads();  // beta: P's T2 writes visible block-wide

    // ---- T2r row0 [P]: read 17t + j ----
    {
        const float* rp = P + P1 * t;
#pragma unroll
        for (int j = 0; j < 16; ++j) u[j] = rp[j];  // in flight
    }
    // ---- T2w row1 [Q] (issue under T2r0 latency) ----
    {
        float* wp = Q + P1 * t_lo + t_hi;
#pragma unroll
        for (int j = 0; j < 16; ++j) wp[(P1 * 16) * j] = w[j];
    }

    // ---- C0 (counted lgkm wait for T2r0 only) ----
    fwht16(u);

    __syncthreads();  // gamma: Q's T2 writes visible (vmcnt outstanding: 0)

    // ---- T2r row1 [Q] ----
    {
        const float* rp = Q + P1 * t;
#pragma unroll
        for (int j = 0; j < 16; ++j) w[j] = rp[j];  // in flight
    }

    // ---- store row0 (NT scalar; overlaps T2r1 latency) ----
    const float scale = 0x1p-39f;  // 2^-(L(L+1)/4), L = 12
    {
        float* dst = y + r0 * DIM + t;
#pragma unroll
        for (int j = 0; j < 16; ++j)
            __builtin_nontemporal_store(u[j] * scale, dst + j * 256);
    }

    // ---- C1 ----
    fwht16(w);

    // ---- store row1 ----
    {
        float* dst = y + (r0 + 1) * DIM + t;
#pragma unroll
        for (int j = 0; j < 16; ++j)
            __builtin_nontemporal_store(w[j] * scale, dst + j * 256);
    }
}

extern "C" void kernel_launch(void* const* d_in, const int* in_sizes, int n_in,
                              void* d_out, int out_size, void* d_ws, size_t ws_size,
                              hipStream_t stream) {
    const float* x = (const float*)d_in[0];
    float* y = (float*)d_out;
    const int nrows = in_sizes[0] / DIM;  // 8192 (even)
    fwht4096_kernel<<<nrows / 2, 256, 0, stream>>>(x, y);
}